// Round 20
// baseline (144.388 us; speedup 1.0000x reference)
//
#include <hip/hip_runtime.h>

#define NN   100000
#define SEQ  12
#define NPB  48                      // nodes per block (3 MFMA node-tiles)
#define XSTR 64                      // sx row stride (floats)
#define RSTR 384                     // B row stride in shorts = NPB*8; 192 dwords == 0 mod 32
#define GRID ((NN + NPB - 1) / NPB)  // 2084 blocks; ~2 blocks/CU resident (R14-proven)

typedef float f32x4 __attribute__((ext_vector_type(4)));
typedef short s16x8 __attribute__((ext_vector_type(8)));

// ---- d_ws float offsets ----
#define OFF_U    0        // [tau][lane][reg] scaled u
#define OFF_V    2048     // [tau][lane][reg] scaled (v + bih0 + bhh0)
#define OFF_B1F  4096     // [tau][lane][reg] scaled (bih1 + bhh1)
#define OFF_FC1  6144     // [m][j] W_fc1^T
#define OFF_BFC1 6656
#define OFF_FC2  6672
#define OFF_BFC2 6688
#define OFF_A    6720     // shorts: A0 [0,8192), A1 [8192,24576)

#define L2E  1.4426950408889634f
#define L2E2 2.8853900817779268f

#if defined(__has_builtin)
#if __has_builtin(__builtin_amdgcn_exp2f)
#define EXP2(x) __builtin_amdgcn_exp2f(x)
#endif
#endif
#ifndef EXP2
#define EXP2(x) exp2f(x)
#endif

__device__ __forceinline__ float rcp_fast(float v) { return __builtin_amdgcn_rcpf(v); }
__device__ __forceinline__ float sigm_p(float a) { return rcp_fast(1.0f + EXP2(a)); }
__device__ __forceinline__ float tanh_p(float a) {
    return fmaf(-2.0f, rcp_fast(1.0f + EXP2(a)), 1.0f);
}
__device__ __forceinline__ unsigned short f2bf(float f) {   // RNE fp32->bf16 (repack)
    unsigned u = __float_as_uint(f);
    u = u + 0x7FFFu + ((u >> 16) & 1u);
    return (unsigned short)(u >> 16);
}
__device__ __forceinline__ float bf2f(unsigned short h) {
    return __uint_as_float(((unsigned)h) << 16);
}
__device__ __forceinline__ void hsplit(float h, unsigned& uh, unsigned& ul) {
    asm("v_cvt_pk_bf16_f32 %0, %1, %1" : "=v"(uh) : "v"(h));
    const float lo = h - __uint_as_float(uh << 16);
    asm("v_cvt_pk_bf16_f32 %0, %1, %1" : "=v"(ul) : "v"(lo));
}

#define MF(a, b, c) __builtin_amdgcn_mfma_f32_16x16x32_bf16((a), (b), (c), 0, 0, 0)

// Repack (layout unchanged from R12-R19): r'=4k+g row order; gate-scale folded
// into ALL preact terms (i,f,o * -log2e ; g * +2log2e); weights hi/lo bf16
// A-fragments in [tau][term][lane][e] order.
__global__ void repack(const float* __restrict__ Wtp,  const float* __restrict__ btp,
                       const float* __restrict__ Wih0, const float* __restrict__ Whh0,
                       const float* __restrict__ bih0, const float* __restrict__ bhh0,
                       const float* __restrict__ Wih1, const float* __restrict__ Whh1,
                       const float* __restrict__ bih1, const float* __restrict__ bhh1,
                       const float* __restrict__ Wfc1, const float* __restrict__ bfc1,
                       const float* __restrict__ Wfc2, const float* __restrict__ bfc2,
                       float* __restrict__ ws)
{
    const int tid = threadIdx.x;  // 256
    for (int idx = tid; idx < 2048; idx += 256) {
        int tau = idx >> 8, lane = (idx >> 2) & 63, reg = idx & 3;
        int grow = 16 * tau + (lane >> 4) * 4 + reg;
        int k = grow >> 2, g = grow & 3;
        int orig = g * 32 + k;
        float sg = (g == 2) ? L2E2 : -L2E;
        float u = 0.f, v = 0.f;
        for (int d = 0; d < 16; ++d) {
            u = fmaf(Wih0[orig * 16 + d], Wtp[d], u);
            v = fmaf(Wih0[orig * 16 + d], btp[d], v);
        }
        ws[OFF_U + idx]   = sg * u;
        ws[OFF_V + idx]   = sg * (v + bih0[orig] + bhh0[orig]);
        ws[OFF_B1F + idx] = sg * (bih1[orig] + bhh1[orig]);
    }
    short* wsS = (short*)(ws + OFF_A);
    for (int idx = tid; idx < 8192; idx += 256) {
        int tau = idx >> 10, t = (idx >> 9) & 1, lane = (idx >> 3) & 63, e = idx & 7;
        int rl = lane & 15, g = rl & 3;
        int orig = g * 32 + 4 * tau + (rl >> 2);
        int j = (lane >> 4) * 8 + e;
        float sg = (g == 2) ? L2E2 : -L2E;
        float f = sg * Whh0[orig * 32 + j];
        unsigned short hi = f2bf(f);
        wsS[idx] = (short)(t == 0 ? hi : f2bf(f - bf2f(hi)));
    }
    for (int idx = tid; idx < 16384; idx += 256) {
        int tau = idx >> 11, kap = (idx >> 10) & 1, t = (idx >> 9) & 1;
        int lane = (idx >> 3) & 63, e = idx & 7;
        int rl = lane & 15, g = rl & 3;
        int orig = g * 32 + 4 * tau + (rl >> 2);
        int j = (lane >> 4) * 8 + e;
        float sg = (g == 2) ? L2E2 : -L2E;
        float f = sg * (kap ? Whh1[orig * 32 + j] : Wih1[orig * 32 + j]);
        unsigned short hi = f2bf(f);
        wsS[8192 + idx] = (short)(t == 0 ? hi : f2bf(f - bf2f(hi)));
    }
    for (int idx = tid; idx < 512; idx += 256) {
        int m = idx >> 5, j = idx & 31;
        ws[OFF_FC1 + idx] = Wfc1[j * 16 + m];
    }
    if (tid < 16) { ws[OFF_BFC1 + tid] = bfc1[tid]; ws[OFF_FC2 + tid] = Wfc2[tid]; }
    if (tid == 0) ws[OFF_BFC2] = bfc2[0];
}

// One LSTM time-step, parity P compile-time. ONE barrier per step (between
// layers; bar2 removed per the R12 hazard audit). L1 uses TWO accumulators
// (Bh0-group, Bh1-group) merged by one add: dependent MFMA chain 6 -> 3.
// (setprio removed: R19 A/B showed neutral-to-negative.)
template<int P>
__device__ __forceinline__ void lstm_step(
    short* __restrict__ B0, short* __restrict__ B1,
    const float*& sxp, float* __restrict__ fin,
    f32x4 uf, f32x4 vf, f32x4 b1f,
    s16x8 A0h, s16x8 A0l, s16x8 A10h, s16x8 A10l, s16x8 A11h, s16x8 A11l,
    float (&c0)[3], float (&c1)[3],
    int col, int lg, int ku, bool last)
{
    constexpr int NP = P ^ 1;
    const int nb = col * 8;
    const short* rb0 = B0 + lg * RSTR + nb;
    const short* rb1 = B1 + lg * RSTR + nb;
    short* wb0 = B0 + (ku >> 3) * RSTR + nb + (ku & 7);
    short* wb1 = B1 + (ku >> 3) * RSTR + nb + (ku & 7);

    // ---- layer 0: reads Bh0[P], writes Bh0[NP] ----
#pragma unroll
    for (int i = 0; i < 3; ++i) {
        const float xv = sxp[i * 16];
        f32x4 acc = { fmaf(uf[0], xv, vf[0]), fmaf(uf[1], xv, vf[1]),
                      fmaf(uf[2], xv, vf[2]), fmaf(uf[3], xv, vf[3]) };
        const s16x8 bh = *(const s16x8*)(rb0 + (P * 8) * RSTR + i * 128);
        const s16x8 bl = *(const s16x8*)(rb0 + (P * 8 + 4) * RSTR + i * 128);
        acc = MF(A0h, bh, acc);
        acc = MF(A0l, bh, acc);
        acc = MF(A0h, bl, acc);
        const float gi = sigm_p(acc[0]);
        const float gf = sigm_p(acc[1]);
        const float gg = tanh_p(acc[2]);
        const float go = sigm_p(acc[3]);
        const float cc = fmaf(gf, c0[i], gi * gg);
        c0[i] = cc;
        const float h = go * tanh_p(L2E2 * cc);
        unsigned uh, ul; hsplit(h, uh, ul);
        wb0[(NP * 8) * RSTR + i * 128]     = (short)uh;
        wb0[(NP * 8 + 4) * RSTR + i * 128] = (short)ul;
    }
    __syncthreads();   // bar1: h0-new complete & visible

    // ---- layer 1: reads Bh0[NP] + Bh1[P], writes Bh1[NP] ----
#pragma unroll
    for (int i = 0; i < 3; ++i) {
        f32x4 accA = { b1f[0], b1f[1], b1f[2], b1f[3] };
        f32x4 accB = { 0.f, 0.f, 0.f, 0.f };
        const s16x8 b0h = *(const s16x8*)(rb0 + (NP * 8) * RSTR + i * 128);
        const s16x8 b0l = *(const s16x8*)(rb0 + (NP * 8 + 4) * RSTR + i * 128);
        const s16x8 b1h = *(const s16x8*)(rb1 + (P * 8) * RSTR + i * 128);
        const s16x8 b1l = *(const s16x8*)(rb1 + (P * 8 + 4) * RSTR + i * 128);
        accA = MF(A10h, b0h, accA);
        accB = MF(A11h, b1h, accB);
        accA = MF(A10l, b0h, accA);
        accB = MF(A11l, b1h, accB);
        accA = MF(A10h, b0l, accA);
        accB = MF(A11h, b1l, accB);
        const f32x4 acc = { accA[0] + accB[0], accA[1] + accB[1],
                            accA[2] + accB[2], accA[3] + accB[3] };
        const float gi = sigm_p(acc[0]);
        const float gf = sigm_p(acc[1]);
        const float gg = tanh_p(acc[2]);
        const float go = sigm_p(acc[3]);
        const float cc = fmaf(gf, c1[i], gi * gg);
        c1[i] = cc;
        const float h = go * tanh_p(L2E2 * cc);
        if (last) {
            // transposed [unit][node]; region = Bh0 parity-1 rows (its last
            // readers, layer0 of this step, finished before bar1 above)
            fin[ku * NPB + col + i * 16] = h;
        } else {
            unsigned uh, ul; hsplit(h, uh, ul);
            wb1[(NP * 8) * RSTR + i * 128]     = (short)uh;
            wb1[(NP * 8 + 4) * RSTR + i * 128] = (short)ul;
        }
    }
    // no end-of-step barrier (R12 audit)
    sxp += XSTR;
}

// 48 nodes/block, 8 waves of 64 (512 thr); wave w = gate-tile tau (units
// 4w..4w+3), each wave covers all 3 node-tiles — the R14 config (best
// measured: 141us, occupancy 52%, 2 blocks/CU). LDS 27.6 KB; 1 barrier/step;
// RSTR == 0 mod 32 geometry; full-sB zeroing.
// R20: fc head parallelized across 3 waves (was 1 wave / 7 idle = ~7% of
// block time): wave w<3 owns 16 nodes; lg-group computes m-quarter;
// shfl_xor(16,32) reduce; lg==0 lane writes.
__global__ __launch_bounds__(512)
void lstm_mfma(const float* __restrict__ x, const float* __restrict__ ws,
               float* __restrict__ out)
{
    __shared__ short sB[2 * 16 * RSTR];   // Bh0 + Bh1, 24 KB
    __shared__ float sx[SEQ][XSTR];       // 3 KB

    const int tid  = threadIdx.x;
    const int lane = tid & 63;
    const int w    = __builtin_amdgcn_readfirstlane(tid >> 6);  // 0..7 = tau
    const int lg   = lane >> 4, col = lane & 15;
    const int ku   = 4 * w + lg;
    const int b0   = blockIdx.x * NPB;

    for (int i = tid; i < SEQ * XSTR; i += 512) {
        int t = i >> 6, nd = i & (XSTR - 1);
        int n = b0 + nd;
        sx[t][nd] = (nd < NPB && n < NN) ? x[(size_t)n * 32 + 20 + t] : 0.f;
    }
    int* z = (int*)sB;
    for (int i = tid; i < 16 * RSTR; i += 512) z[i] = 0;   // ALL of sB

    const f32x4 uf  = *(const f32x4*)(ws + OFF_U   + (w * 64 + lane) * 4);
    const f32x4 vf  = *(const f32x4*)(ws + OFF_V   + (w * 64 + lane) * 4);
    const f32x4 b1f = *(const f32x4*)(ws + OFF_B1F + (w * 64 + lane) * 4);
    const short* AS  = (const short*)(ws + OFF_A);
    const s16x8 A0h  = *(const s16x8*)(AS + ((w * 2 + 0) * 64 + lane) * 8);
    const s16x8 A0l  = *(const s16x8*)(AS + ((w * 2 + 1) * 64 + lane) * 8);
    const short* AS1 = AS + 8192;
    const s16x8 A10h = *(const s16x8*)(AS1 + ((w * 4 + 0) * 64 + lane) * 8);
    const s16x8 A10l = *(const s16x8*)(AS1 + ((w * 4 + 1) * 64 + lane) * 8);
    const s16x8 A11h = *(const s16x8*)(AS1 + ((w * 4 + 2) * 64 + lane) * 8);
    const s16x8 A11l = *(const s16x8*)(AS1 + ((w * 4 + 3) * 64 + lane) * 8);

    short* B0 = sB;
    short* B1 = sB + 16 * RSTR;
    float* fin = (float*)(B0 + 8 * RSTR);   // Bh0 parity-1 region, [unit][node]

    float c0[3], c1[3];
#pragma unroll
    for (int i = 0; i < 3; ++i) { c0[i] = 0.f; c1[i] = 0.f; }

    __syncthreads();

    const float* sxp = &sx[0][0] + col;
#pragma unroll 1
    for (int tt = 0; tt < SEQ / 2; ++tt) {
        lstm_step<0>(B0, B1, sxp, fin, uf, vf, b1f,
                     A0h, A0l, A10h, A10l, A11h, A11l,
                     c0, c1, col, lg, ku, false);
        lstm_step<1>(B0, B1, sxp, fin, uf, vf, b1f,
                     A0h, A0l, A10h, A10l, A11h, A11l,
                     c0, c1, col, lg, ku, tt == SEQ / 2 - 1);
    }

    __syncthreads();   // fin complete & visible

    // ---- fc head: waves 0-2, wave w owns nodes [16w,16w+16); lg-group
    // computes m-quarter [4lg,4lg+4); reduce over lg via shfl_xor 16/32.
    if (w < 3) {
        const int nd = w * 16 + col;
        float hreg[32];
#pragma unroll
        for (int j = 0; j < 32; ++j)
            hreg[j] = fin[j * NPB + nd];      // 4 lanes same addr -> broadcast
        float part = 0.f;
#pragma unroll
        for (int mm = 0; mm < 4; ++mm) {
            const int m = lg * 4 + mm;
            const float* fp = ws + OFF_FC1 + m * 32;
            float y = ws[OFF_BFC1 + m];
#pragma unroll
            for (int j = 0; j < 32; ++j)
                y = fmaf(fp[j], hreg[j], y);
            part = fmaf(fmaxf(y, 0.f), ws[OFF_FC2 + m], part);
        }
        part += __shfl_xor(part, 16, 64);
        part += __shfl_xor(part, 32, 64);
        if (lg == 0 && b0 + nd < NN)
            out[b0 + nd] = part + ws[OFF_BFC2];
    }
}

extern "C" void kernel_launch(void* const* d_in, const int* in_sizes, int n_in,
                              void* d_out, int out_size, void* d_ws, size_t ws_size,
                              hipStream_t stream) {
    (void)in_sizes; (void)n_in; (void)out_size; (void)ws_size;
    const float* x    = (const float*)d_in[0];
    // d_in[1] edge_index and d_in[2..9] (GCN weights) are dead code in the reference
    const float* Wtp  = (const float*)d_in[10];
    const float* btp  = (const float*)d_in[11];
    const float* Wih0 = (const float*)d_in[12];
    const float* Whh0 = (const float*)d_in[13];
    const float* bih0 = (const float*)d_in[14];
    const float* bhh0 = (const float*)d_in[15];
    const float* Wih1 = (const float*)d_in[16];
    const float* Whh1 = (const float*)d_in[17];
    const float* bih1 = (const float*)d_in[18];
    const float* bhh1 = (const float*)d_in[19];
    const float* Wfc1 = (const float*)d_in[20];
    const float* bfc1 = (const float*)d_in[21];
    const float* Wfc2 = (const float*)d_in[22];
    const float* bfc2 = (const float*)d_in[23];
    float* ws  = (float*)d_ws;
    float* out = (float*)d_out;

    hipLaunchKernelGGL(repack, dim3(1), dim3(256), 0, stream,
                       Wtp, btp, Wih0, Whh0, bih0, bhh0,
                       Wih1, Whh1, bih1, bhh1, Wfc1, bfc1, Wfc2, bfc2, ws);
    hipLaunchKernelGGL(lstm_mfma, dim3(GRID), dim3(512), 0, stream,
                       x, ws, out);
}

// Round 21
// 141.145 us; speedup vs baseline: 1.0230x; 1.0230x over previous
//
#include <hip/hip_runtime.h>

#define NN   100000
#define SEQ  12
#define NPB  48                      // nodes per block (3 MFMA node-tiles)
#define XSTR 64                      // sx row stride (floats)
#define RSTR 384                     // B row stride in shorts = NPB*8; 192 dwords == 0 mod 32
#define GRID ((NN + NPB - 1) / NPB)  // 2084 blocks; ~2 blocks/CU resident

typedef float f32x4 __attribute__((ext_vector_type(4)));
typedef short s16x8 __attribute__((ext_vector_type(8)));

// ---- d_ws float offsets ----
#define OFF_U    0        // [tau][lane][reg] scaled u
#define OFF_V    2048     // [tau][lane][reg] scaled (v + bih0 + bhh0)
#define OFF_B1F  4096     // [tau][lane][reg] scaled (bih1 + bhh1)
#define OFF_FC1  6144     // [m][j] W_fc1^T
#define OFF_BFC1 6656
#define OFF_FC2  6672
#define OFF_BFC2 6688
#define OFF_A    6720     // shorts: A0 [0,8192), A1 [8192,24576)

#define L2E  1.4426950408889634f
#define L2E2 2.8853900817779268f

#if defined(__has_builtin)
#if __has_builtin(__builtin_amdgcn_exp2f)
#define EXP2(x) __builtin_amdgcn_exp2f(x)
#endif
#endif
#ifndef EXP2
#define EXP2(x) exp2f(x)
#endif

__device__ __forceinline__ float rcp_fast(float v) { return __builtin_amdgcn_rcpf(v); }
__device__ __forceinline__ float sigm_p(float a) { return rcp_fast(1.0f + EXP2(a)); }
__device__ __forceinline__ float tanh_p(float a) {
    return fmaf(-2.0f, rcp_fast(1.0f + EXP2(a)), 1.0f);
}
__device__ __forceinline__ unsigned short f2bf(float f) {   // RNE fp32->bf16 (repack)
    unsigned u = __float_as_uint(f);
    u = u + 0x7FFFu + ((u >> 16) & 1u);
    return (unsigned short)(u >> 16);
}
__device__ __forceinline__ float bf2f(unsigned short h) {
    return __uint_as_float(((unsigned)h) << 16);
}
__device__ __forceinline__ void hsplit(float h, unsigned& uh, unsigned& ul) {
    asm("v_cvt_pk_bf16_f32 %0, %1, %1" : "=v"(uh) : "v"(h));
    const float lo = h - __uint_as_float(uh << 16);
    asm("v_cvt_pk_bf16_f32 %0, %1, %1" : "=v"(ul) : "v"(lo));
}

#define MF(a, b, c) __builtin_amdgcn_mfma_f32_16x16x32_bf16((a), (b), (c), 0, 0, 0)

// Repack: r'=4k+g row order; gate-scale folded into ALL preact terms
// (i,f,o rows * -log2e ; g rows * +2log2e); weights hi/lo bf16 A-fragments.
__global__ void repack(const float* __restrict__ Wtp,  const float* __restrict__ btp,
                       const float* __restrict__ Wih0, const float* __restrict__ Whh0,
                       const float* __restrict__ bih0, const float* __restrict__ bhh0,
                       const float* __restrict__ Wih1, const float* __restrict__ Whh1,
                       const float* __restrict__ bih1, const float* __restrict__ bhh1,
                       const float* __restrict__ Wfc1, const float* __restrict__ bfc1,
                       const float* __restrict__ Wfc2, const float* __restrict__ bfc2,
                       float* __restrict__ ws)
{
    const int tid = threadIdx.x;  // 256
    for (int idx = tid; idx < 2048; idx += 256) {
        int tau = idx >> 8, lane = (idx >> 2) & 63, reg = idx & 3;
        int grow = 16 * tau + (lane >> 4) * 4 + reg;
        int k = grow >> 2, g = grow & 3;
        int orig = g * 32 + k;
        float sg = (g == 2) ? L2E2 : -L2E;
        float u = 0.f, v = 0.f;
        for (int d = 0; d < 16; ++d) {
            u = fmaf(Wih0[orig * 16 + d], Wtp[d], u);
            v = fmaf(Wih0[orig * 16 + d], btp[d], v);
        }
        ws[OFF_U + idx]   = sg * u;
        ws[OFF_V + idx]   = sg * (v + bih0[orig] + bhh0[orig]);
        ws[OFF_B1F + idx] = sg * (bih1[orig] + bhh1[orig]);
    }
    short* wsS = (short*)(ws + OFF_A);
    for (int idx = tid; idx < 8192; idx += 256) {
        int tau = idx >> 10, t = (idx >> 9) & 1, lane = (idx >> 3) & 63, e = idx & 7;
        int rl = lane & 15, g = rl & 3;
        int orig = g * 32 + 4 * tau + (rl >> 2);
        int j = (lane >> 4) * 8 + e;
        float sg = (g == 2) ? L2E2 : -L2E;
        float f = sg * Whh0[orig * 32 + j];
        unsigned short hi = f2bf(f);
        wsS[idx] = (short)(t == 0 ? hi : f2bf(f - bf2f(hi)));
    }
    for (int idx = tid; idx < 16384; idx += 256) {
        int tau = idx >> 11, kap = (idx >> 10) & 1, t = (idx >> 9) & 1;
        int lane = (idx >> 3) & 63, e = idx & 7;
        int rl = lane & 15, g = rl & 3;
        int orig = g * 32 + 4 * tau + (rl >> 2);
        int j = (lane >> 4) * 8 + e;
        float sg = (g == 2) ? L2E2 : -L2E;
        float f = sg * (kap ? Whh1[orig * 32 + j] : Wih1[orig * 32 + j]);
        unsigned short hi = f2bf(f);
        wsS[8192 + idx] = (short)(t == 0 ? hi : f2bf(f - bf2f(hi)));
    }
    for (int idx = tid; idx < 512; idx += 256) {
        int m = idx >> 5, j = idx & 31;
        ws[OFF_FC1 + idx] = Wfc1[j * 16 + m];
    }
    if (tid < 16) { ws[OFF_BFC1 + tid] = bfc1[tid]; ws[OFF_FC2 + tid] = Wfc2[tid]; }
    if (tid == 0) ws[OFF_BFC2] = bfc2[0];
}

// One LSTM time-step, parity P compile-time. ONE barrier per step (between
// layers); bar2 removed per the R12 hazard audit (layer1(t)'s Bh1[np] writes
// are next read by layer1(t+1) behind bar1(t+1); layer0(t+1)'s Bh0 writes
// only touch rows whose readers finished before bar1(t)).
template<int P>
__device__ __forceinline__ void lstm_step(
    short* __restrict__ B0, short* __restrict__ B1,
    const float*& sxp, float* __restrict__ fin,
    f32x4 uf, f32x4 vf, f32x4 b1f,
    s16x8 A0h, s16x8 A0l, s16x8 A10h, s16x8 A10l, s16x8 A11h, s16x8 A11l,
    float (&c0)[3], float (&c1)[3],
    int col, int lg, int ku, bool last)
{
    constexpr int NP = P ^ 1;
    const int nb = col * 8;
    const short* rb0 = B0 + lg * RSTR + nb;
    const short* rb1 = B1 + lg * RSTR + nb;
    short* wb0 = B0 + (ku >> 3) * RSTR + nb + (ku & 7);
    short* wb1 = B1 + (ku >> 3) * RSTR + nb + (ku & 7);

    // ---- layer 0: reads Bh0[P], writes Bh0[NP] ----
#pragma unroll
    for (int i = 0; i < 3; ++i) {
        const float xv = sxp[i * 16];
        f32x4 acc = { fmaf(uf[0], xv, vf[0]), fmaf(uf[1], xv, vf[1]),
                      fmaf(uf[2], xv, vf[2]), fmaf(uf[3], xv, vf[3]) };
        const s16x8 bh = *(const s16x8*)(rb0 + (P * 8) * RSTR + i * 128);
        const s16x8 bl = *(const s16x8*)(rb0 + (P * 8 + 4) * RSTR + i * 128);
        acc = MF(A0h, bh, acc);
        acc = MF(A0l, bh, acc);
        acc = MF(A0h, bl, acc);
        const float gi = sigm_p(acc[0]);
        const float gf = sigm_p(acc[1]);
        const float gg = tanh_p(acc[2]);
        const float go = sigm_p(acc[3]);
        const float cc = fmaf(gf, c0[i], gi * gg);
        c0[i] = cc;
        const float h = go * tanh_p(L2E2 * cc);
        unsigned uh, ul; hsplit(h, uh, ul);
        wb0[(NP * 8) * RSTR + i * 128]     = (short)uh;
        wb0[(NP * 8 + 4) * RSTR + i * 128] = (short)ul;
    }
    __syncthreads();   // bar1: h0-new complete & visible

    // ---- layer 1: reads Bh0[NP] + Bh1[P], writes Bh1[NP] ----
#pragma unroll
    for (int i = 0; i < 3; ++i) {
        f32x4 acc = { b1f[0], b1f[1], b1f[2], b1f[3] };
        const s16x8 b0h = *(const s16x8*)(rb0 + (NP * 8) * RSTR + i * 128);
        const s16x8 b0l = *(const s16x8*)(rb0 + (NP * 8 + 4) * RSTR + i * 128);
        const s16x8 b1h = *(const s16x8*)(rb1 + (P * 8) * RSTR + i * 128);
        const s16x8 b1l = *(const s16x8*)(rb1 + (P * 8 + 4) * RSTR + i * 128);
        acc = MF(A10h, b0h, acc);
        acc = MF(A10l, b0h, acc);
        acc = MF(A10h, b0l, acc);
        acc = MF(A11h, b1h, acc);
        acc = MF(A11l, b1h, acc);
        acc = MF(A11h, b1l, acc);
        const float gi = sigm_p(acc[0]);
        const float gf = sigm_p(acc[1]);
        const float gg = tanh_p(acc[2]);
        const float go = sigm_p(acc[3]);
        const float cc = fmaf(gf, c1[i], gi * gg);
        c1[i] = cc;
        const float h = go * tanh_p(L2E2 * cc);
        if (last) {
            // transposed [unit][node]; region = Bh0 parity-1 rows (its last
            // readers, layer0 of this step, finished before bar1 above)
            fin[ku * NPB + col + i * 16] = h;
        } else {
            unsigned uh, ul; hsplit(h, uh, ul);
            wb1[(NP * 8) * RSTR + i * 128]     = (short)uh;
            wb1[(NP * 8 + 4) * RSTR + i * 128] = (short)ul;
        }
    }
    // no end-of-step barrier (audit above)
    sxp += XSTR;
}

// 48 nodes/block, 8 waves of 64 (512 thr); wave w = gate-tile tau (units
// 4w..4w+3), each wave covers all 3 node-tiles. The measured champion config
// (R14: 141us, occupancy 52%, 2 blocks/CU, VGPR 36). LDS 27.6 KB;
// 1 barrier/step; RSTR == 0 mod 32 geometry; full-sB zeroing.
// Verified-neutral-or-worse variants (reverted): setprio (R19), L1 acc
// chain-split (R19/R20), 3-wave fc head (R20: VGPR 40->56, occ 52->37).
__global__ __launch_bounds__(512)
void lstm_mfma(const float* __restrict__ x, const float* __restrict__ ws,
               float* __restrict__ out)
{
    __shared__ short sB[2 * 16 * RSTR];   // Bh0 + Bh1, 24 KB
    __shared__ float sx[SEQ][XSTR];       // 3 KB

    const int tid  = threadIdx.x;
    const int lane = tid & 63;
    const int w    = __builtin_amdgcn_readfirstlane(tid >> 6);  // 0..7 = tau
    const int lg   = lane >> 4, col = lane & 15;
    const int ku   = 4 * w + lg;
    const int b0   = blockIdx.x * NPB;

    for (int i = tid; i < SEQ * XSTR; i += 512) {
        int t = i >> 6, nd = i & (XSTR - 1);
        int n = b0 + nd;
        sx[t][nd] = (nd < NPB && n < NN) ? x[(size_t)n * 32 + 20 + t] : 0.f;
    }
    int* z = (int*)sB;
    for (int i = tid; i < 16 * RSTR; i += 512) z[i] = 0;   // ALL of sB

    const f32x4 uf  = *(const f32x4*)(ws + OFF_U   + (w * 64 + lane) * 4);
    const f32x4 vf  = *(const f32x4*)(ws + OFF_V   + (w * 64 + lane) * 4);
    const f32x4 b1f = *(const f32x4*)(ws + OFF_B1F + (w * 64 + lane) * 4);
    const short* AS  = (const short*)(ws + OFF_A);
    const s16x8 A0h  = *(const s16x8*)(AS + ((w * 2 + 0) * 64 + lane) * 8);
    const s16x8 A0l  = *(const s16x8*)(AS + ((w * 2 + 1) * 64 + lane) * 8);
    const short* AS1 = AS + 8192;
    const s16x8 A10h = *(const s16x8*)(AS1 + ((w * 4 + 0) * 64 + lane) * 8);
    const s16x8 A10l = *(const s16x8*)(AS1 + ((w * 4 + 1) * 64 + lane) * 8);
    const s16x8 A11h = *(const s16x8*)(AS1 + ((w * 4 + 2) * 64 + lane) * 8);
    const s16x8 A11l = *(const s16x8*)(AS1 + ((w * 4 + 3) * 64 + lane) * 8);

    short* B0 = sB;
    short* B1 = sB + 16 * RSTR;
    float* fin = (float*)(B0 + 8 * RSTR);   // Bh0 parity-1 region, [unit][node]

    float c0[3], c1[3];
#pragma unroll
    for (int i = 0; i < 3; ++i) { c0[i] = 0.f; c1[i] = 0.f; }

    __syncthreads();

    const float* sxp = &sx[0][0] + col;
#pragma unroll 1
    for (int tt = 0; tt < SEQ / 2; ++tt) {
        lstm_step<0>(B0, B1, sxp, fin, uf, vf, b1f,
                     A0h, A0l, A10h, A10l, A11h, A11l,
                     c0, c1, col, lg, ku, false);
        lstm_step<1>(B0, B1, sxp, fin, uf, vf, b1f,
                     A0h, A0l, A10h, A10l, A11h, A11l,
                     c0, c1, col, lg, ku, tt == SEQ / 2 - 1);
    }

    __syncthreads();   // fin complete & visible

    // ---- fc head: wave 0, one node per lane (lane < NPB) ----
    if (w == 0 && lane < NPB) {
        const int nd = lane;
        float acc2 = ws[OFF_BFC2];
#pragma unroll
        for (int m = 0; m < 16; ++m) {
            const float* fp = ws + OFF_FC1 + m * 32;   // uniform -> s_load
            float y = ws[OFF_BFC1 + m];
#pragma unroll
            for (int j = 0; j < 32; ++j)
                y = fmaf(fp[j], fin[j * NPB + nd], y);
            acc2 = fmaf(fmaxf(y, 0.f), ws[OFF_FC2 + m], acc2);
        }
        if (b0 + nd < NN) out[b0 + nd] = acc2;
    }
}

extern "C" void kernel_launch(void* const* d_in, const int* in_sizes, int n_in,
                              void* d_out, int out_size, void* d_ws, size_t ws_size,
                              hipStream_t stream) {
    (void)in_sizes; (void)n_in; (void)out_size; (void)ws_size;
    const float* x    = (const float*)d_in[0];
    // d_in[1] edge_index and d_in[2..9] (GCN weights) are dead code in the reference
    const float* Wtp  = (const float*)d_in[10];
    const float* btp  = (const float*)d_in[11];
    const float* Wih0 = (const float*)d_in[12];
    const float* Whh0 = (const float*)d_in[13];
    const float* bih0 = (const float*)d_in[14];
    const float* bhh0 = (const float*)d_in[15];
    const float* Wih1 = (const float*)d_in[16];
    const float* Whh1 = (const float*)d_in[17];
    const float* bih1 = (const float*)d_in[18];
    const float* bhh1 = (const float*)d_in[19];
    const float* Wfc1 = (const float*)d_in[20];
    const float* bfc1 = (const float*)d_in[21];
    const float* Wfc2 = (const float*)d_in[22];
    const float* bfc2 = (const float*)d_in[23];
    float* ws  = (float*)d_ws;
    float* out = (float*)d_out;

    hipLaunchKernelGGL(repack, dim3(1), dim3(256), 0, stream,
                       Wtp, btp, Wih0, Whh0, bih0, bhh0,
                       Wih1, Whh1, bih1, bhh1, Wfc1, bfc1, Wfc2, bfc2, ws);
    hipLaunchKernelGGL(lstm_mfma, dim3(GRID), dim3(512), 0, stream,
                       x, ws, out);
}